// Round 6
// baseline (328.714 us; speedup 1.0000x reference)
//
#include <hip/hip_runtime.h>
#include <math.h>

// Problem constants (B=1 hardcoded).
#define M_TOT 8192
#define NXY   192
#define NPIX  (192*192)   // 36864
#define NC    8
#define REC   20          // floats per packed record (80B, 16B-aligned)

// ---------------------------------------------------------------------------
// Kernel 1: pack per-m records:
//   [wr0,wi0,...,wr7,wi7, kx, ky, cos(ky), sin(ky)]
// w[c,m] = (kr + i ki)[c,m] * dc[m]
// cos/sin(ky) feed the y+1 angle-addition rotation in adj_main.
// ---------------------------------------------------------------------------
__global__ __launch_bounds__(256) void pack_kernel(
    const float* __restrict__ kr, const float* __restrict__ ki,
    const float* __restrict__ traj, const float* __restrict__ dc,
    float* __restrict__ pack)
{
    int m = blockIdx.x * 256 + threadIdx.x;
    if (m >= M_TOT) return;
    float d = dc[m];
    float* r = pack + (size_t)m * REC;
#pragma unroll
    for (int c = 0; c < NC; ++c) {
        r[2*c]   = kr[c*M_TOT + m] * d;
        r[2*c+1] = ki[c*M_TOT + m] * d;
    }
    float ky = traj[M_TOT + m];
    r[16] = traj[m];   // kx
    r[17] = ky;        // ky
    r[18] = cosf(ky);  // rotation for y -> y+1
    r[19] = sinf(ky);
}

// ---------------------------------------------------------------------------
// Kernel 2: main adjoint loop. 2 pixels/thread (p0=2t even -> p0,p0+1 share
// the same x row). Pixel 1's phase factor comes from rotating pixel 0's by
// exp(i*ky): halves sin/cos (TRANS pipe) per pixel and halves wave count.
// Accumulators are float2 (.x=pixel0, .y=pixel1) with structurally identical
// fmaf chains per component -> SLP-vectorizable to v_pk_fma_f32.
// All per-m loads are wave-uniform -> scalar (s_load) path.
// partial layout: [(split*NC + c) * NPIX + p] as float2 (re, im)
// ---------------------------------------------------------------------------
__global__ __launch_bounds__(256) void adj_main(
    const float* __restrict__ pack, float* __restrict__ partial, int mch)
{
    const int t = blockIdx.x * 256 + threadIdx.x;   // over NPIX/2 threads
    const int split = blockIdx.y;
    const int p0 = t * 2;
    const float gx  = (float)(p0 / NXY - NXY/2);
    const float gy0 = (float)(p0 % NXY - NXY/2);

    float2 par[NC], pai[NC];
#pragma unroll
    for (int c = 0; c < NC; ++c) {
        par[c] = make_float2(0.f, 0.f);
        pai[c] = make_float2(0.f, 0.f);
    }

    const float inv2pi = 0.15915494309189535f;
    const float* rec = pack + (size_t)split * mch * REC;

    for (int m = 0; m < mch; ++m, rec += REC) {
        const float4* r4 = (const float4*)rec;
        float4 w01 = r4[0];
        float4 w23 = r4[1];
        float4 w45 = r4[2];
        float4 w67 = r4[3];
        float4 tkk = r4[4];     // x=kx y=ky z=cos(ky) w=sin(ky)

        float ph = fmaf(tkk.x, gx, tkk.y * gy0);
        // revolutions in [0,1): v_fract_f32 (|ph|*inv2pi <= ~96, in range)
        float r  = __builtin_amdgcn_fractf(ph * inv2pi);
        float s0 = __builtin_amdgcn_sinf(r);   // sin(phase0)
        float c0 = __builtin_amdgcn_cosf(r);   // cos(phase0)
        // pixel1 = rotate by exp(i*ky): phase1 = phase0 + ky
        float c1 = fmaf(c0, tkk.z, -(s0 * tkk.w));
        float s1 = fmaf(s0, tkk.z,  (c0 * tkk.w));

        // (wr + i wi) * (c + i s) accumulated per pixel (x: p0, y: p0+1)
#define COIL(WR, WI, IDX)                                                \
        par[IDX].x = fmaf((WR), c0, fmaf(-(WI), s0, par[IDX].x));        \
        par[IDX].y = fmaf((WR), c1, fmaf(-(WI), s1, par[IDX].y));        \
        pai[IDX].x = fmaf((WR), s0, fmaf( (WI), c0, pai[IDX].x));        \
        pai[IDX].y = fmaf((WR), s1, fmaf( (WI), c1, pai[IDX].y));
        COIL(w01.x, w01.y, 0)
        COIL(w01.z, w01.w, 1)
        COIL(w23.x, w23.y, 2)
        COIL(w23.z, w23.w, 3)
        COIL(w45.x, w45.y, 4)
        COIL(w45.z, w45.w, 5)
        COIL(w67.x, w67.y, 6)
        COIL(w67.z, w67.w, 7)
#undef COIL
    }

#pragma unroll
    for (int c = 0; c < NC; ++c) {
        // (re0, im0, re1, im1) for adjacent pixels p0, p0+1; 16B-aligned
        // since p0 is even (p0*8B offset) and the per-coil base is 16B-mult.
        float4 v = make_float4(par[c].x, pai[c].x, par[c].y, pai[c].y);
        *(float4*)(partial + ((size_t)(split*NC + c)*NPIX + p0)*2) = v;
    }
}

// ---------------------------------------------------------------------------
// Kernel 3: reduce splits, coil-combine with conj(smaps), magnitude.
// ---------------------------------------------------------------------------
__global__ __launch_bounds__(256) void combine_kernel(
    const float* __restrict__ partial,
    const float* __restrict__ smr, const float* __restrict__ smi,
    float* __restrict__ out, int nsplit)
{
    const int p = blockIdx.x * 256 + threadIdx.x;
    float cr[NC], ci[NC];
#pragma unroll
    for (int c = 0; c < NC; ++c) { cr[c] = 0.f; ci[c] = 0.f; }

    for (int s = 0; s < nsplit; ++s) {
#pragma unroll
        for (int c = 0; c < NC; ++c) {
            float2 v = *(const float2*)(partial + ((size_t)(s*NC + c)*NPIX + p)*2);
            cr[c] += v.x; ci[c] += v.y;
        }
    }

    float re = 0.f, im = 0.f;
#pragma unroll
    for (int c = 0; c < NC; ++c) {
        float sr = smr[c*NPIX + p];
        float si = smi[c*NPIX + p];
        // (cr + i ci) * (sr - i si)
        re += cr[c]*sr + ci[c]*si;
        im += ci[c]*sr - cr[c]*si;
    }
    out[p] = sqrtf(re*re + im*im);
}

// ---------------------------------------------------------------------------
// Fallback: single kernel, no workspace (in case ws_size is too small).
// Simple proven 1-pixel/thread formulation — correctness anchor.
// ---------------------------------------------------------------------------
__global__ __launch_bounds__(256) void adj_fallback(
    const float* __restrict__ kr, const float* __restrict__ ki,
    const float* __restrict__ traj, const float* __restrict__ dc,
    const float* __restrict__ smr, const float* __restrict__ smi,
    float* __restrict__ out)
{
    const int p = blockIdx.x * 256 + threadIdx.x;
    const float gx = (float)(p / NXY - NXY/2);
    const float gy = (float)(p % NXY - NXY/2);

    float ar[NC], ai[NC];
#pragma unroll
    for (int c = 0; c < NC; ++c) { ar[c] = 0.f; ai[c] = 0.f; }

    const float inv2pi = 0.15915494309189535f;
    for (int m = 0; m < M_TOT; ++m) {
        float kx = traj[m];
        float ky = traj[M_TOT + m];
        float d  = dc[m];
        float ph = fmaf(kx, gx, ky * gy);
        float r  = __builtin_amdgcn_fractf(ph * inv2pi);
        float s = __builtin_amdgcn_sinf(r);
        float c = __builtin_amdgcn_cosf(r);
#pragma unroll
        for (int cc = 0; cc < NC; ++cc) {
            float wr = kr[cc*M_TOT + m] * d;
            float wi = ki[cc*M_TOT + m] * d;
            ar[cc] = fmaf(wr, c, fmaf(-wi, s, ar[cc]));
            ai[cc] = fmaf(wr, s, fmaf( wi, c, ai[cc]));
        }
    }

    float re = 0.f, im = 0.f;
#pragma unroll
    for (int c = 0; c < NC; ++c) {
        float sr = smr[c*NPIX + p];
        float si = smi[c*NPIX + p];
        re += ar[c]*sr + ai[c]*si;
        im += ai[c]*sr - ar[c]*si;
    }
    out[p] = sqrtf(re*re + im*im);
}

// ---------------------------------------------------------------------------
extern "C" void kernel_launch(void* const* d_in, const int* in_sizes, int n_in,
                              void* d_out, int out_size, void* d_ws, size_t ws_size,
                              hipStream_t stream)
{
    const float* kr   = (const float*)d_in[0];  // kspace_real  [1,8,8192]
    const float* ki   = (const float*)d_in[1];  // kspace_imag  [1,8,8192]
    const float* traj = (const float*)d_in[2];  // trajectory   [2,8192]
    const float* smr  = (const float*)d_in[3];  // smaps_real   [1,8,192,192]
    const float* smi  = (const float*)d_in[4];  // smaps_imag   [1,8,192,192]
    const float* dc   = (const float*)d_in[5];  // density_comp [8192]
    float* out = (float*)d_out;                 // [1,192,192,1] fp32

    const size_t pack_bytes = (size_t)M_TOT * REC * sizeof(float);  // 640 KB

    // Pick the largest split whose partial buffer fits in the workspace.
    // partial bytes = split * NC * NPIX * 2 * 4 B  (split=32 -> ~75.5 MB)
    int split = 0;
    for (int s = 32; s >= 8; s >>= 1) {
        size_t need = pack_bytes + (size_t)s * NC * NPIX * 2 * sizeof(float);
        if (ws_size >= need) { split = s; break; }
    }

    if (split > 0) {
        float* pack    = (float*)d_ws;
        float* partial = pack + (size_t)M_TOT * REC;
        int mch = M_TOT / split;
        pack_kernel<<<(M_TOT + 255)/256, 256, 0, stream>>>(kr, ki, traj, dc, pack);
        // 2 pixels/thread -> NPIX/2 threads per split (18432 = 72 blocks)
        adj_main<<<dim3(NPIX/2/256, split), 256, 0, stream>>>(pack, partial, mch);
        combine_kernel<<<NPIX/256, 256, 0, stream>>>(partial, smr, smi, out, split);
    } else {
        adj_fallback<<<NPIX/256, 256, 0, stream>>>(kr, ki, traj, dc, smr, smi, out);
    }
}

// Round 7
// 145.535 us; speedup vs baseline: 2.2587x; 2.2587x over previous
//
#include <hip/hip_runtime.h>
#include <math.h>

// Problem constants (B=1 hardcoded).
#define M_TOT 8192
#define NXY   192
#define NPIX  (192*192)   // 36864
#define NC    8
#define REC   20          // floats per packed record (fp32 fallback path)

// MFMA path geometry: one real GEMM C[M=1536, N'=384] = A[1536,16384] x B[16384,384]
//   rows r=(c*192+y), cols n'=2x+{re,im}, k'=2m+{re,im}
//   A[r,2m]=Re(w*Ey), A[r,2m+1]=Im(w*Ey);  B stored transposed BT[n'][k']:
//   BT[2x]  [2m,2m+1] = ( cos,-sin)(kx*gx)
//   BT[2x+1][2m,2m+1] = ( sin, cos)(kx*gx)
#define GM 1536
#define GN 384
#define GK 16384
#define KSPLIT 4
#define KCH (GK/KSPLIT)   // 4096
#define BK 64             // k'-elems per LDS step
#define NSTEP (KCH/BK)    // 64

typedef _Float16 fp16;
typedef fp16 f16x8 __attribute__((ext_vector_type(8)));
typedef float f32x4 __attribute__((ext_vector_type(4)));

#define INV2PI 0.15915494309189535f

// ---------------------------------------------------------------------------
// MFMA path kernel 1: A[r=(c*192+y), k'=2m+{0,1}] = w[c,m]*Ey[m,y]  (fp16)
// thread = y*8192 + m (m fastest -> coalesced stores per coil).
// ---------------------------------------------------------------------------
__global__ __launch_bounds__(256) void pack_A_mfma(
    const float* __restrict__ kr, const float* __restrict__ ki,
    const float* __restrict__ traj, const float* __restrict__ dc,
    fp16* __restrict__ A)
{
    int tid = blockIdx.x * 256 + threadIdx.x;   // 192*8192
    int y = tid >> 13;
    int m = tid & 8191;
    float ky = traj[M_TOT + m];
    float d  = dc[m];
    float gy = (float)(y - 96);
    float r  = __builtin_amdgcn_fractf(ky * gy * INV2PI);
    float s  = __builtin_amdgcn_sinf(r);
    float c  = __builtin_amdgcn_cosf(r);
    unsigned int* A2 = (unsigned int*)A;        // half2 stores
#pragma unroll
    for (int cc = 0; cc < NC; ++cc) {
        float wr = kr[cc*M_TOT + m] * d;
        float wi = ki[cc*M_TOT + m] * d;
        float re = wr*c - wi*s;
        float im = wr*s + wi*c;
        union { fp16 h[2]; unsigned int u; } p;
        p.h[0] = (fp16)re; p.h[1] = (fp16)im;
        A2[(size_t)(cc*NXY + y) * (GK/2) + m] = p.u;
    }
}

// ---------------------------------------------------------------------------
// MFMA path kernel 2: BT[n'=2x+e][k'=2m+g]  (fp16, transposed for GEMM staging)
// thread = x*8192 + m.
// ---------------------------------------------------------------------------
__global__ __launch_bounds__(256) void pack_B_mfma(
    const float* __restrict__ traj, fp16* __restrict__ BT)
{
    int tid = blockIdx.x * 256 + threadIdx.x;   // 192*8192
    int x = tid >> 13;
    int m = tid & 8191;
    float kx = traj[m];
    float gx = (float)(x - 96);
    float r  = __builtin_amdgcn_fractf(kx * gx * INV2PI);
    float s  = __builtin_amdgcn_sinf(r);
    float c  = __builtin_amdgcn_cosf(r);
    unsigned int* B2 = (unsigned int*)BT;
    union { fp16 h[2]; unsigned int u; } p0, p1;
    p0.h[0] = (fp16)c;  p0.h[1] = (fp16)(-s);   // row 2x:   (c, -s)
    p1.h[0] = (fp16)s;  p1.h[1] = (fp16)c;      // row 2x+1: (s,  c)
    B2[(size_t)x * GK + m]            = p0.u;   // = ((2x)*GK + 2m)/2
    B2[(size_t)x * GK + (GK/2) + m]   = p1.u;   // = ((2x+1)*GK + 2m)/2
}

// ---------------------------------------------------------------------------
// MFMA path kernel 3: split-K GEMM, 64x64 block tile, 4 waves (2x2 of 32x32),
// f16 MFMA 16x16x32, single-LDS-buffer 2-barrier loop with register prefetch.
// partial[kz][GM][GN] f32.
// ---------------------------------------------------------------------------
__global__ __launch_bounds__(256) void gemm_f16(
    const fp16* __restrict__ A, const fp16* __restrict__ BT,
    float* __restrict__ partial)
{
    __shared__ __align__(16) fp16 a_s[64][72];  // +8 halves pad: 2-way bank max
    __shared__ __align__(16) fp16 b_s[64][72];

    const int tm = blockIdx.x / (GN/64);        // 0..23
    const int tn = blockIdx.x % (GN/64);        // 0..5
    const int kz = blockIdx.y;                  // 0..KSPLIT-1
    const int r0 = tm * 64, n0 = tn * 64;

    const int t   = threadIdx.x;
    const int row = t >> 2;                     // 0..63 (staging row)
    const int seg = t & 3;                      // 0..3  (32B segment)
    const fp16* pA = A  + (size_t)(r0 + row) * GK + kz*KCH + seg*16;
    const fp16* pB = BT + (size_t)(n0 + row) * GK + kz*KCH + seg*16;

    const int w  = t >> 6, wm = w >> 1, wn = w & 1;
    const int lane = t & 63, lr = lane & 15, lk = lane >> 4;

    f32x4 acc[2][2] = {};

    uint4 ra0 = *(const uint4*)(pA);
    uint4 ra1 = *(const uint4*)(pA + 8);
    uint4 rb0 = *(const uint4*)(pB);
    uint4 rb1 = *(const uint4*)(pB + 8);

    for (int step = 0; step < NSTEP; ++step) {
        __syncthreads();                        // prev step's reads done
        *(uint4*)&a_s[row][seg*16]     = ra0;
        *(uint4*)&a_s[row][seg*16 + 8] = ra1;
        *(uint4*)&b_s[row][seg*16]     = rb0;
        *(uint4*)&b_s[row][seg*16 + 8] = rb1;
        __syncthreads();                        // writes visible

        // prefetch next step (last iter reads past chunk: stays inside ws)
        const fp16* nA = pA + (step+1)*BK;
        const fp16* nB = pB + (step+1)*BK;
        ra0 = *(const uint4*)(nA);
        ra1 = *(const uint4*)(nA + 8);
        rb0 = *(const uint4*)(nB);
        rb1 = *(const uint4*)(nB + 8);

#pragma unroll
        for (int kk = 0; kk < 2; ++kk) {
            const int ko = kk*32 + lk*8;
            f16x8 a0 = *(const f16x8*)&a_s[wm*32 +      lr][ko];
            f16x8 a1 = *(const f16x8*)&a_s[wm*32 + 16 + lr][ko];
            f16x8 b0 = *(const f16x8*)&b_s[wn*32 +      lr][ko];
            f16x8 b1 = *(const f16x8*)&b_s[wn*32 + 16 + lr][ko];
            acc[0][0] = __builtin_amdgcn_mfma_f32_16x16x32_f16(a0, b0, acc[0][0], 0, 0, 0);
            acc[0][1] = __builtin_amdgcn_mfma_f32_16x16x32_f16(a0, b1, acc[0][1], 0, 0, 0);
            acc[1][0] = __builtin_amdgcn_mfma_f32_16x16x32_f16(a1, b0, acc[1][0], 0, 0, 0);
            acc[1][1] = __builtin_amdgcn_mfma_f32_16x16x32_f16(a1, b1, acc[1][1], 0, 0, 0);
        }
    }

    float* P = partial + (size_t)kz * GM * GN;
#pragma unroll
    for (int mi = 0; mi < 2; ++mi)
#pragma unroll
        for (int nj = 0; nj < 2; ++nj) {
            const int gcol = n0 + wn*32 + nj*16 + lr;
#pragma unroll
            for (int reg = 0; reg < 4; ++reg) {
                const int grow = r0 + wm*32 + mi*16 + lk*4 + reg;
                P[(size_t)grow * GN + gcol] = acc[mi][nj][reg];
            }
        }
}

// ---------------------------------------------------------------------------
// MFMA path kernel 4: reduce split-K, coil-combine with conj(smaps), abs.
// thread: x fastest (partial cols 2x -> near-coalesced).
// ---------------------------------------------------------------------------
__global__ __launch_bounds__(256) void combine_mfma(
    const float* __restrict__ partial,
    const float* __restrict__ smr, const float* __restrict__ smi,
    float* __restrict__ out)
{
    int t = blockIdx.x * 256 + threadIdx.x;     // 36864
    int y = t / NXY, x = t % NXY;
    float ore = 0.f, oim = 0.f;
#pragma unroll
    for (int c = 0; c < NC; ++c) {
        int rrow = c*NXY + y;
        float re = 0.f, im = 0.f;
#pragma unroll
        for (int kzz = 0; kzz < KSPLIT; ++kzz) {
            const float2 v = *(const float2*)(partial +
                ((size_t)kzz*GM + rrow) * GN + 2*x);
            re += v.x; im += v.y;
        }
        float sr = smr[c*NPIX + x*NXY + y];
        float si = smi[c*NPIX + x*NXY + y];
        ore += re*sr + im*si;                   // * conj(smap)
        oim += im*sr - re*si;
    }
    out[x*NXY + y] = sqrtf(ore*ore + oim*oim);
}

// ===========================================================================
// fp32 fallback path (proven correct @328us) — used if ws too small.
// ===========================================================================
__global__ __launch_bounds__(256) void pack_kernel(
    const float* __restrict__ kr, const float* __restrict__ ki,
    const float* __restrict__ traj, const float* __restrict__ dc,
    float* __restrict__ pack)
{
    int m = blockIdx.x * 256 + threadIdx.x;
    if (m >= M_TOT) return;
    float d = dc[m];
    float* r = pack + (size_t)m * REC;
#pragma unroll
    for (int c = 0; c < NC; ++c) {
        r[2*c]   = kr[c*M_TOT + m] * d;
        r[2*c+1] = ki[c*M_TOT + m] * d;
    }
    float ky = traj[M_TOT + m];
    r[16] = traj[m];
    r[17] = ky;
    r[18] = cosf(ky);
    r[19] = sinf(ky);
}

__global__ __launch_bounds__(256) void adj_main(
    const float* __restrict__ pack, float* __restrict__ partial, int mch)
{
    const int t = blockIdx.x * 256 + threadIdx.x;
    const int split = blockIdx.y;
    const int p0 = t * 2;
    const float gx  = (float)(p0 / NXY - NXY/2);
    const float gy0 = (float)(p0 % NXY - NXY/2);

    float2 par[NC], pai[NC];
#pragma unroll
    for (int c = 0; c < NC; ++c) {
        par[c] = make_float2(0.f, 0.f);
        pai[c] = make_float2(0.f, 0.f);
    }
    const float* rec = pack + (size_t)split * mch * REC;
    for (int m = 0; m < mch; ++m, rec += REC) {
        const float4* r4 = (const float4*)rec;
        float4 w01 = r4[0], w23 = r4[1], w45 = r4[2], w67 = r4[3], tkk = r4[4];
        float ph = fmaf(tkk.x, gx, tkk.y * gy0);
        float r  = __builtin_amdgcn_fractf(ph * INV2PI);
        float s0 = __builtin_amdgcn_sinf(r);
        float c0 = __builtin_amdgcn_cosf(r);
        float c1 = fmaf(c0, tkk.z, -(s0 * tkk.w));
        float s1 = fmaf(s0, tkk.z,  (c0 * tkk.w));
#define COIL(WR, WI, IDX)                                                \
        par[IDX].x = fmaf((WR), c0, fmaf(-(WI), s0, par[IDX].x));        \
        par[IDX].y = fmaf((WR), c1, fmaf(-(WI), s1, par[IDX].y));        \
        pai[IDX].x = fmaf((WR), s0, fmaf( (WI), c0, pai[IDX].x));        \
        pai[IDX].y = fmaf((WR), s1, fmaf( (WI), c1, pai[IDX].y));
        COIL(w01.x, w01.y, 0) COIL(w01.z, w01.w, 1)
        COIL(w23.x, w23.y, 2) COIL(w23.z, w23.w, 3)
        COIL(w45.x, w45.y, 4) COIL(w45.z, w45.w, 5)
        COIL(w67.x, w67.y, 6) COIL(w67.z, w67.w, 7)
#undef COIL
    }
#pragma unroll
    for (int c = 0; c < NC; ++c) {
        float4 v = make_float4(par[c].x, pai[c].x, par[c].y, pai[c].y);
        *(float4*)(partial + ((size_t)(split*NC + c)*NPIX + p0)*2) = v;
    }
}

__global__ __launch_bounds__(256) void combine_kernel(
    const float* __restrict__ partial,
    const float* __restrict__ smr, const float* __restrict__ smi,
    float* __restrict__ out, int nsplit)
{
    const int p = blockIdx.x * 256 + threadIdx.x;
    float cr[NC], ci[NC];
#pragma unroll
    for (int c = 0; c < NC; ++c) { cr[c] = 0.f; ci[c] = 0.f; }
    for (int s = 0; s < nsplit; ++s)
#pragma unroll
        for (int c = 0; c < NC; ++c) {
            float2 v = *(const float2*)(partial + ((size_t)(s*NC + c)*NPIX + p)*2);
            cr[c] += v.x; ci[c] += v.y;
        }
    float re = 0.f, im = 0.f;
#pragma unroll
    for (int c = 0; c < NC; ++c) {
        float sr = smr[c*NPIX + p];
        float si = smi[c*NPIX + p];
        re += cr[c]*sr + ci[c]*si;
        im += ci[c]*sr - cr[c]*si;
    }
    out[p] = sqrtf(re*re + im*im);
}

__global__ __launch_bounds__(256) void adj_fallback(
    const float* __restrict__ kr, const float* __restrict__ ki,
    const float* __restrict__ traj, const float* __restrict__ dc,
    const float* __restrict__ smr, const float* __restrict__ smi,
    float* __restrict__ out)
{
    const int p = blockIdx.x * 256 + threadIdx.x;
    const float gx = (float)(p / NXY - NXY/2);
    const float gy = (float)(p % NXY - NXY/2);
    float ar[NC], ai[NC];
#pragma unroll
    for (int c = 0; c < NC; ++c) { ar[c] = 0.f; ai[c] = 0.f; }
    for (int m = 0; m < M_TOT; ++m) {
        float kx = traj[m];
        float ky = traj[M_TOT + m];
        float d  = dc[m];
        float ph = fmaf(kx, gx, ky * gy);
        float r  = __builtin_amdgcn_fractf(ph * INV2PI);
        float s = __builtin_amdgcn_sinf(r);
        float c = __builtin_amdgcn_cosf(r);
#pragma unroll
        for (int cc = 0; cc < NC; ++cc) {
            float wr = kr[cc*M_TOT + m] * d;
            float wi = ki[cc*M_TOT + m] * d;
            ar[cc] = fmaf(wr, c, fmaf(-wi, s, ar[cc]));
            ai[cc] = fmaf(wr, s, fmaf( wi, c, ai[cc]));
        }
    }
    float re = 0.f, im = 0.f;
#pragma unroll
    for (int c = 0; c < NC; ++c) {
        float sr = smr[c*NPIX + p];
        float si = smi[c*NPIX + p];
        re += ar[c]*sr + ai[c]*si;
        im += ai[c]*sr - ar[c]*si;
    }
    out[p] = sqrtf(re*re + im*im);
}

// ---------------------------------------------------------------------------
extern "C" void kernel_launch(void* const* d_in, const int* in_sizes, int n_in,
                              void* d_out, int out_size, void* d_ws, size_t ws_size,
                              hipStream_t stream)
{
    const float* kr   = (const float*)d_in[0];
    const float* ki   = (const float*)d_in[1];
    const float* traj = (const float*)d_in[2];
    const float* smr  = (const float*)d_in[3];
    const float* smi  = (const float*)d_in[4];
    const float* dc   = (const float*)d_in[5];
    float* out = (float*)d_out;

    const size_t A_bytes = (size_t)GM * GK * sizeof(fp16);        // 50.33 MB
    const size_t B_bytes = (size_t)GN * GK * sizeof(fp16);        // 12.58 MB
    const size_t P_bytes = (size_t)KSPLIT * GM * GN * sizeof(float); // 9.44 MB
    const size_t need_mfma = A_bytes + B_bytes + P_bytes;         // 72.35 MB

    if (ws_size >= need_mfma) {
        fp16*  A  = (fp16*)d_ws;
        fp16*  BT = (fp16*)((char*)d_ws + A_bytes);
        float* P  = (float*)((char*)d_ws + A_bytes + B_bytes);
        pack_A_mfma<<<(NXY*M_TOT)/256, 256, 0, stream>>>(kr, ki, traj, dc, A);
        pack_B_mfma<<<(NXY*M_TOT)/256, 256, 0, stream>>>(traj, BT);
        gemm_f16<<<dim3((GM/64)*(GN/64), KSPLIT), 256, 0, stream>>>(A, BT, P);
        combine_mfma<<<NPIX/256, 256, 0, stream>>>(P, smr, smi, out);
        return;
    }

    const size_t pack_bytes = (size_t)M_TOT * REC * sizeof(float);
    int split = 0;
    for (int s = 32; s >= 8; s >>= 1) {
        size_t need = pack_bytes + (size_t)s * NC * NPIX * 2 * sizeof(float);
        if (ws_size >= need) { split = s; break; }
    }
    if (split > 0) {
        float* pack    = (float*)d_ws;
        float* partial = pack + (size_t)M_TOT * REC;
        int mch = M_TOT / split;
        pack_kernel<<<(M_TOT + 255)/256, 256, 0, stream>>>(kr, ki, traj, dc, pack);
        adj_main<<<dim3(NPIX/2/256, split), 256, 0, stream>>>(pack, partial, mch);
        combine_kernel<<<NPIX/256, 256, 0, stream>>>(partial, smr, smi, out, split);
    } else {
        adj_fallback<<<NPIX/256, 256, 0, stream>>>(kr, ki, traj, dc, smr, smi, out);
    }
}